// Round 1
// baseline (379.823 us; speedup 1.0000x reference)
//
#include <hip/hip_runtime.h>

#define N_ 100000
#define E_ 600000
#define IND_ 128
#define OUTD_ 256
#define NT_ (N_/16)   // 6250 row-tiles of 16

typedef __attribute__((ext_vector_type(8))) short bf16x8;
typedef __attribute__((ext_vector_type(4))) float f32x4;
typedef __attribute__((ext_vector_type(2))) unsigned int u32x2;

static __device__ __forceinline__ unsigned f2bf_u(float f){
  union { float f; unsigned u; } v; v.f = f;
  return (v.u + 0x7fffu + ((v.u >> 16) & 1u)) >> 16;   // RNE bf16
}
static __device__ __forceinline__ unsigned pack2(float a, float b){
  return f2bf_u(a) | (f2bf_u(b) << 16);
}

// ---- weight prep: fp32 row-major W[K][256] -> bf16 fragment-order, chunked for 32KB LDS stages
// unit u = q*2048 + (t*2+km)*64 + l ; kk = 2q+km ; element j: W[(kk*32 + (l>>4)*8 + j)][16t + (l&15)]
__global__ void k_prep(const float* __restrict__ W1, const float* __restrict__ W2,
                       const float* __restrict__ Wp, const float* __restrict__ b2,
                       const float* __restrict__ gamma, const float* __restrict__ beta,
                       const float* __restrict__ mean, const float* __restrict__ var,
                       const float* __restrict__ bp,
                       unsigned short* __restrict__ W1s, unsigned short* __restrict__ W2s,
                       unsigned short* __restrict__ Wps,
                       float* __restrict__ scale, float* __restrict__ shift)
{
  int gid = blockIdx.x*256 + threadIdx.x;
  if (gid < 16384) {
    const float* W; unsigned short* Ws; int u;
    if (gid < 4096)       { W = W1; Ws = W1s; u = gid; }
    else if (gid < 12288) { W = W2; Ws = W2s; u = gid - 4096; }
    else                  { W = Wp; Ws = Wps; u = gid - 12288; }
    int l  = u & 63;
    int km = (u >> 6) & 1;
    int t  = (u >> 7) & 15;
    int q  = u >> 11;
    int kk = 2*q + km;
    int kb = kk*32 + (l >> 4)*8;
    int c  = 16*t + (l & 15);
    #pragma unroll
    for (int j = 0; j < 8; j++)
      Ws[u*8 + j] = (unsigned short)f2bf_u(W[(size_t)(kb + j)*OUTD_ + c]);
  } else if (gid < 16640) {
    int c = gid - 16384;
    float s = gamma[c] * rsqrtf(var[c] + 1e-5f);
    scale[c] = s;
    shift[c] = (b2[c] - mean[c]) * s + beta[c] + bp[c];
  }
}

__global__ void k_deg(const int* __restrict__ dst, int* __restrict__ deg){
  int e = blockIdx.x*256 + threadIdx.x;
  if (e < E_) atomicAdd(&deg[dst[e]], 1);
}

__global__ __launch_bounds__(1024) void k_scan(const int* __restrict__ deg, int* __restrict__ offs){
  __shared__ int sums[1024];
  int tid = threadIdx.x;
  const int CH = (N_ + 1023)/1024;   // 98
  int beg = tid*CH, end = min(beg + CH, N_);
  int s = 0;
  for (int i = beg; i < end; i++) s += deg[i];
  sums[tid] = s; __syncthreads();
  for (int d = 1; d < 1024; d <<= 1){
    int v = (tid >= d) ? sums[tid - d] : 0;
    __syncthreads();
    sums[tid] += v;
    __syncthreads();
  }
  int run = (tid > 0) ? sums[tid - 1] : 0;   // exclusive prefix of this chunk
  for (int i = beg; i < end; i++){ offs[i] = run; run += deg[i]; }
  if (tid == 1023) offs[N_] = E_;
}

__global__ void k_fill(const int* __restrict__ src, const int* __restrict__ dst,
                       const int* __restrict__ offs, int* __restrict__ cur, int* __restrict__ adj){
  int e = blockIdx.x*256 + threadIdx.x;
  if (e < E_) {
    int d = dst[e];
    int p = atomicAdd(&cur[d], 1);
    adj[offs[d] + p] = src[e];
  }
}

// one wave per dst row; lane holds cols {2L, 2L+1}; writes h0=(1+eps)x+agg and x as bf16
__global__ void k_agg(const float* __restrict__ x, const int* __restrict__ offs,
                      const int* __restrict__ adj, const float* __restrict__ epsp,
                      unsigned* __restrict__ h0, unsigned* __restrict__ xb)
{
  int row  = blockIdx.x*4 + (threadIdx.x >> 6);
  int lane = threadIdx.x & 63;
  if (row >= N_) return;
  const float2* xr = (const float2*)(x + (size_t)row*IND_);
  float2 xv = xr[lane];
  float ax = 0.f, ay = 0.f;
  int b = offs[row], e = offs[row+1];
  for (int i = b; i < e; i++){
    const float2* p = (const float2*)(x + (size_t)adj[i]*IND_);
    float2 v = p[lane];
    ax += v.x; ay += v.y;
  }
  float k1 = 1.f + epsp[0];
  h0[(size_t)row*64 + lane] = pack2(fmaf(k1, xv.x, ax), fmaf(k1, xv.y, ay));
  xb[(size_t)row*64 + lane] = pack2(xv.x, xv.y);
}

// GEMM1: h1 = relu(h0 @ W1 + b1), swapped-operand MFMA; h1 written in B-fragment order:
// h1s unit (tile, kk, lane) = 16B, lane l holds h1[tile*16 + (l&15)][kk*32 + (l>>4)*8 .. +8]
__global__ __launch_bounds__(256) void k_mlp1(const unsigned short* __restrict__ h0,
        const bf16x8* __restrict__ W1s, const float* __restrict__ b1,
        unsigned short* __restrict__ h1s)
{
  __shared__ bf16x8 w[2048];                       // 32KB weight chunk
  __shared__ __align__(16) char trans[4][2][1280]; // per-wave 16x(64B+16B pad), double-buffered
  int tid = threadIdx.x;
  int wv = tid >> 6, lane = tid & 63, g = lane >> 4, r = lane & 15;
  int tile0 = blockIdx.x*4 + wv;
  int tile  = min(tile0, NT_ - 1);

  const bf16x8* hrow = (const bf16x8*)(h0 + ((size_t)tile*16 + r)*IND_);
  bf16x8 B[4];
  #pragma unroll
  for (int kk = 0; kk < 4; kk++) B[kk] = hrow[kk*4 + g];

  f32x4 acc[16];
  #pragma unroll
  for (int t = 0; t < 16; t++) acc[t] = (f32x4){0.f,0.f,0.f,0.f};

  for (int q = 0; q < 2; q++){
    __syncthreads();
    #pragma unroll
    for (int i = 0; i < 8; i++) w[tid + i*256] = W1s[q*2048 + tid + i*256];
    __syncthreads();
    #pragma unroll
    for (int km = 0; km < 2; km++){
      bf16x8 Bf = B[2*q + km];
      #pragma unroll
      for (int t = 0; t < 16; t++)
        acc[t] = __builtin_amdgcn_mfma_f32_16x16x32_bf16(w[(t*2+km)*64 + lane], Bf, acc[t], 0,0,0);
    }
  }

  // epilogue: bias+relu -> bf16, per-32-col LDS regroup (4g+q -> 8g+j), coalesced frag-order store
  const float4* b1v = (const float4*)b1;
  unsigned short* outp = h1s + (size_t)tile*4096;
  bool act = (tile0 < NT_);
  #pragma unroll
  for (int kkh = 0; kkh < 8; kkh++){
    char* tr = &trans[wv][kkh & 1][0];
    #pragma unroll
    for (int h = 0; h < 2; h++){
      int t = 2*kkh + h;
      float4 bb = b1v[t*4 + g];
      f32x4 a = acc[t];
      float v0 = fmaxf(a.x + bb.x, 0.f);
      float v1 = fmaxf(a.y + bb.y, 0.f);
      float v2 = fmaxf(a.z + bb.z, 0.f);
      float v3 = fmaxf(a.w + bb.w, 0.f);
      u32x2 dd; dd.x = pack2(v0, v1); dd.y = pack2(v2, v3);
      *(u32x2*)(tr + r*80 + h*32 + g*8) = dd;   // row r, cols 16h+4g..+3
    }
    bf16x8 frag = *(const bf16x8*)(tr + r*80 + g*16);   // row r, cols 8g..8g+7
    if (act) *(bf16x8*)(outp + (kkh*64 + lane)*8) = frag;
  }
}

// GEMM2+proj: out = (h1 @ W2) * scale + shift + x @ Wp  (swapped-operand, same acc)
__global__ __launch_bounds__(256) void k_mlp2(const bf16x8* __restrict__ h1s,
        const unsigned short* __restrict__ xb,
        const bf16x8* __restrict__ W2s, const bf16x8* __restrict__ Wps,
        const float* __restrict__ scale, const float* __restrict__ shift,
        float* __restrict__ out)
{
  __shared__ bf16x8 w[2048];   // 32KB weight chunk
  int tid = threadIdx.x, wv = tid >> 6, lane = tid & 63, g = lane >> 4, r = lane & 15;
  int tile0 = blockIdx.x*4 + wv;
  int tile  = min(tile0, NT_ - 1);
  const bf16x8* h1f  = h1s + (size_t)tile*512;
  const bf16x8* xrow = (const bf16x8*)(xb + ((size_t)tile*16 + r)*IND_);

  f32x4 acc[16];
  #pragma unroll
  for (int t = 0; t < 16; t++) acc[t] = (f32x4){0.f,0.f,0.f,0.f};

  for (int q = 0; q < 4; q++){                       // K=256 of W2 in 4 chunks
    __syncthreads();
    #pragma unroll
    for (int i = 0; i < 8; i++) w[tid + i*256] = W2s[q*2048 + tid + i*256];
    __syncthreads();
    #pragma unroll
    for (int km = 0; km < 2; km++){
      bf16x8 Bf = h1f[(2*q + km)*64 + lane];
      #pragma unroll
      for (int t = 0; t < 16; t++)
        acc[t] = __builtin_amdgcn_mfma_f32_16x16x32_bf16(w[(t*2+km)*64 + lane], Bf, acc[t], 0,0,0);
    }
  }
  for (int q = 0; q < 2; q++){                       // K=128 of Wp in 2 chunks
    __syncthreads();
    #pragma unroll
    for (int i = 0; i < 8; i++) w[tid + i*256] = Wps[q*2048 + tid + i*256];
    __syncthreads();
    #pragma unroll
    for (int km = 0; km < 2; km++){
      bf16x8 Bf = xrow[(2*q + km)*4 + g];
      #pragma unroll
      for (int t = 0; t < 16; t++)
        acc[t] = __builtin_amdgcn_mfma_f32_16x16x32_bf16(w[(t*2+km)*64 + lane], Bf, acc[t], 0,0,0);
    }
  }

  if (tile0 < NT_){
    const float4* sc = (const float4*)scale;
    const float4* sh = (const float4*)shift;
    #pragma unroll
    for (int t = 0; t < 16; t++){
      float4 s = sc[t*4 + g], b = sh[t*4 + g];
      f32x4 a = acc[t];
      float4 o;
      o.x = fmaf(a.x, s.x, b.x);
      o.y = fmaf(a.y, s.y, b.y);
      o.z = fmaf(a.z, s.z, b.z);
      o.w = fmaf(a.w, s.w, b.w);
      *(float4*)(out + ((size_t)tile*16 + r)*OUTD_ + t*16 + g*4) = o;
    }
  }
}

extern "C" void kernel_launch(void* const* d_in, const int* in_sizes, int n_in,
                              void* d_out, int out_size, void* d_ws, size_t ws_size,
                              hipStream_t stream)
{
  const float* x     = (const float*)d_in[0];
  const int*   ei    = (const int*)d_in[1];     // [2][E]: src then dst
  const float* eps   = (const float*)d_in[2];
  const float* W1    = (const float*)d_in[3];
  const float* b1    = (const float*)d_in[4];
  const float* W2    = (const float*)d_in[5];
  const float* b2    = (const float*)d_in[6];
  const float* gamma = (const float*)d_in[7];
  const float* beta  = (const float*)d_in[8];
  const float* rmean = (const float*)d_in[9];
  const float* rvar  = (const float*)d_in[10];
  const float* Wp    = (const float*)d_in[11];
  const float* bp    = (const float*)d_in[12];
  float* out = (float*)d_out;

  char* ws = (char*)d_ws; size_t off = 0;
  auto carve = [&](size_t b)->char* { char* p = ws + off; off = (off + b + 255) & ~(size_t)255; return p; };
  unsigned*       h0    = (unsigned*)carve((size_t)N_*IND_*2);
  unsigned*       xbuf  = (unsigned*)carve((size_t)N_*IND_*2);
  unsigned short* h1s   = (unsigned short*)carve((size_t)N_*OUTD_*2);
  unsigned short* W1s   = (unsigned short*)carve(4096*16);
  unsigned short* W2s   = (unsigned short*)carve(8192*16);
  unsigned short* Wps   = (unsigned short*)carve(4096*16);
  float*          scale = (float*)carve(256*4);
  float*          shift = (float*)carve(256*4);
  int*            deg   = (int*)carve((size_t)N_*4);
  int*            cur   = (int*)carve((size_t)N_*4);
  int*            offs  = (int*)carve((size_t)(N_+1)*4);
  int*            adj   = (int*)carve((size_t)E_*4);

  hipMemsetAsync(deg, 0, (size_t)N_*4, stream);
  hipMemsetAsync(cur, 0, (size_t)N_*4, stream);

  k_prep<<<65, 256, 0, stream>>>(W1, W2, Wp, b2, gamma, beta, rmean, rvar, bp,
                                 W1s, W2s, Wps, scale, shift);
  k_deg <<<(E_+255)/256, 256, 0, stream>>>(ei + E_, deg);
  k_scan<<<1, 1024, 0, stream>>>(deg, offs);
  k_fill<<<(E_+255)/256, 256, 0, stream>>>(ei, ei + E_, offs, cur, adj);
  k_agg <<<(N_+3)/4, 256, 0, stream>>>(x, offs, adj, eps, h0, xbuf);
  k_mlp1<<<(NT_+3)/4, 256, 0, stream>>>((const unsigned short*)h0, (const bf16x8*)W1s, b1, h1s);
  k_mlp2<<<(NT_+3)/4, 256, 0, stream>>>((const bf16x8*)h1s, (const unsigned short*)xbuf,
                                        (const bf16x8*)W2s, (const bf16x8*)Wps, scale, shift, out);
}

// Round 2
// 231.772 us; speedup vs baseline: 1.6388x; 1.6388x over previous
//
#include <hip/hip_runtime.h>

#define N_ 100000
#define E_ 600000
#define IND_ 128
#define OUTD_ 256
#define NT_ (N_/16)        // 6250 row-tiles of 16
#define NB_ 98             // scan blocks of 1024: ceil(100000/1024)

typedef __attribute__((ext_vector_type(8))) short bf16x8;
typedef __attribute__((ext_vector_type(4))) float f32x4;
typedef __attribute__((ext_vector_type(2))) unsigned int u32x2;

static __device__ __forceinline__ unsigned f2bf_u(float f){
  union { float f; unsigned u; } v; v.f = f;
  return (v.u + 0x7fffu + ((v.u >> 16) & 1u)) >> 16;   // RNE bf16
}
static __device__ __forceinline__ unsigned pack2(float a, float b){
  return f2bf_u(a) | (f2bf_u(b) << 16);
}

// ---- weight prep: fp32 row-major W[K][256] -> bf16 fragment-order, chunked for 32KB LDS stages
__global__ void k_prep(const float* __restrict__ W1, const float* __restrict__ W2,
                       const float* __restrict__ Wp, const float* __restrict__ b2,
                       const float* __restrict__ gamma, const float* __restrict__ beta,
                       const float* __restrict__ mean, const float* __restrict__ var,
                       const float* __restrict__ bp,
                       unsigned short* __restrict__ W1s, unsigned short* __restrict__ W2s,
                       unsigned short* __restrict__ Wps,
                       float* __restrict__ scale, float* __restrict__ shift)
{
  int gid = blockIdx.x*256 + threadIdx.x;
  if (gid < 16384) {
    const float* W; unsigned short* Ws; int u;
    if (gid < 4096)       { W = W1; Ws = W1s; u = gid; }
    else if (gid < 12288) { W = W2; Ws = W2s; u = gid - 4096; }
    else                  { W = Wp; Ws = Wps; u = gid - 12288; }
    int l  = u & 63;
    int km = (u >> 6) & 1;
    int t  = (u >> 7) & 15;
    int q  = u >> 11;
    int kk = 2*q + km;
    int kb = kk*32 + (l >> 4)*8;
    int c  = 16*t + (l & 15);
    #pragma unroll
    for (int j = 0; j < 8; j++)
      Ws[u*8 + j] = (unsigned short)f2bf_u(W[(size_t)(kb + j)*OUTD_ + c]);
  } else if (gid < 16640) {
    int c = gid - 16384;
    float s = gamma[c] * rsqrtf(var[c] + 1e-5f);
    scale[c] = s;
    shift[c] = (b2[c] - mean[c]) * s + beta[c] + bp[c];
  }
}

__global__ void k_deg(const int* __restrict__ dst, int* __restrict__ deg){
  int e = blockIdx.x*256 + threadIdx.x;
  if (e < E_) atomicAdd(&deg[dst[e]], 1);
}

// hierarchical scan pass 1: per-1024-chunk sums (coalesced, full-machine parallel)
__global__ __launch_bounds__(1024) void k_scan1(const int* __restrict__ deg,
                                                int* __restrict__ bsum, int* __restrict__ offs){
  __shared__ int red[16];
  int tid = threadIdx.x;
  int i = blockIdx.x*1024 + tid;
  int v = (i < N_) ? deg[i] : 0;
  #pragma unroll
  for (int d = 32; d; d >>= 1) v += __shfl_down(v, d);
  if ((tid & 63) == 0) red[tid >> 6] = v;
  __syncthreads();
  if (tid < 16) {
    int s = red[tid];
    #pragma unroll
    for (int d = 8; d; d >>= 1) s += __shfl_down(s, d, 16);
    if (tid == 0) bsum[blockIdx.x] = s;
  }
  if (blockIdx.x == 0 && tid == 0) offs[N_] = E_;
}

// pass 2: each block scans the 98 block sums (redundantly) + its own chunk, writes exclusive offsets
__global__ __launch_bounds__(1024) void k_scan2(const int* __restrict__ deg,
                                                const int* __restrict__ bsum, int* __restrict__ offs){
  __shared__ int bs[128];
  __shared__ int d1[1024];
  int tid = threadIdx.x;
  if (tid < 128) bs[tid] = (tid < NB_) ? bsum[tid] : 0;
  __syncthreads();
  #pragma unroll
  for (int d = 1; d < 128; d <<= 1){
    int v = (tid < 128 && tid >= d) ? bs[tid - d] : 0;
    __syncthreads();
    if (tid < 128) bs[tid] += v;
    __syncthreads();
  }
  int bprefix = (blockIdx.x > 0) ? bs[blockIdx.x - 1] : 0;
  int i = blockIdx.x*1024 + tid;
  int v = (i < N_) ? deg[i] : 0;
  d1[tid] = v;
  __syncthreads();
  #pragma unroll
  for (int d = 1; d < 1024; d <<= 1){
    int t = (tid >= d) ? d1[tid - d] : 0;
    __syncthreads();
    d1[tid] += t;
    __syncthreads();
  }
  if (i < N_) offs[i] = bprefix + d1[tid] - v;
}

__global__ void k_fill(const int* __restrict__ src, const int* __restrict__ dst,
                       const int* __restrict__ offs, int* __restrict__ cur, int* __restrict__ adj){
  int e = blockIdx.x*256 + threadIdx.x;
  if (e < E_) {
    int d = dst[e];
    int p = atomicAdd(&cur[d], 1);
    adj[offs[d] + p] = src[e];
  }
}

// one wave per dst row; lane holds cols {2L, 2L+1}; writes h0=(1+eps)x+agg and x as bf16
__global__ void k_agg(const float* __restrict__ x, const int* __restrict__ offs,
                      const int* __restrict__ adj, const float* __restrict__ epsp,
                      unsigned* __restrict__ h0, unsigned* __restrict__ xb)
{
  int row  = blockIdx.x*4 + (threadIdx.x >> 6);
  int lane = threadIdx.x & 63;
  if (row >= N_) return;
  const float2* xr = (const float2*)(x + (size_t)row*IND_);
  float2 xv = xr[lane];
  float ax = 0.f, ay = 0.f;
  int b = offs[row], e = offs[row+1];
  for (int i = b; i < e; i++){
    const float2* p = (const float2*)(x + (size_t)adj[i]*IND_);
    float2 v = p[lane];
    ax += v.x; ay += v.y;
  }
  float k1 = 1.f + epsp[0];
  h0[(size_t)row*64 + lane] = pack2(fmaf(k1, xv.x, ax), fmaf(k1, xv.y, ay));
  xb[(size_t)row*64 + lane] = pack2(xv.x, xv.y);
}

// GEMM1: h1 = relu(h0 @ W1 + b1), swapped-operand MFMA; h1 written in B-fragment order
__global__ __launch_bounds__(256) void k_mlp1(const unsigned short* __restrict__ h0,
        const bf16x8* __restrict__ W1s, const float* __restrict__ b1,
        unsigned short* __restrict__ h1s)
{
  __shared__ bf16x8 w[2048];                       // 32KB weight chunk
  __shared__ __align__(16) char trans[4][2][1280]; // per-wave 16x(64B+16B pad), double-buffered
  int tid = threadIdx.x;
  int wv = tid >> 6, lane = tid & 63, g = lane >> 4, r = lane & 15;
  int tile0 = blockIdx.x*4 + wv;
  int tile  = min(tile0, NT_ - 1);

  const bf16x8* hrow = (const bf16x8*)(h0 + ((size_t)tile*16 + r)*IND_);
  bf16x8 B[4];
  #pragma unroll
  for (int kk = 0; kk < 4; kk++) B[kk] = hrow[kk*4 + g];

  f32x4 acc[16];
  #pragma unroll
  for (int t = 0; t < 16; t++) acc[t] = (f32x4){0.f,0.f,0.f,0.f};

  for (int q = 0; q < 2; q++){
    __syncthreads();
    #pragma unroll
    for (int i = 0; i < 8; i++) w[tid + i*256] = W1s[q*2048 + tid + i*256];
    __syncthreads();
    #pragma unroll
    for (int km = 0; km < 2; km++){
      bf16x8 Bf = B[2*q + km];
      #pragma unroll
      for (int t = 0; t < 16; t++)
        acc[t] = __builtin_amdgcn_mfma_f32_16x16x32_bf16(w[(t*2+km)*64 + lane], Bf, acc[t], 0,0,0);
    }
  }

  // epilogue: bias+relu -> bf16, per-32-col LDS regroup (4g+q -> 8g+j), coalesced frag-order store
  const float4* b1v = (const float4*)b1;
  unsigned short* outp = h1s + (size_t)tile*4096;
  bool act = (tile0 < NT_);
  #pragma unroll
  for (int kkh = 0; kkh < 8; kkh++){
    char* tr = &trans[wv][kkh & 1][0];
    #pragma unroll
    for (int h = 0; h < 2; h++){
      int t = 2*kkh + h;
      float4 bb = b1v[t*4 + g];
      f32x4 a = acc[t];
      float v0 = fmaxf(a.x + bb.x, 0.f);
      float v1 = fmaxf(a.y + bb.y, 0.f);
      float v2 = fmaxf(a.z + bb.z, 0.f);
      float v3 = fmaxf(a.w + bb.w, 0.f);
      u32x2 dd; dd.x = pack2(v0, v1); dd.y = pack2(v2, v3);
      *(u32x2*)(tr + r*80 + h*32 + g*8) = dd;   // row r, cols 16h+4g..+3
    }
    bf16x8 frag = *(const bf16x8*)(tr + r*80 + g*16);   // row r, cols 8g..8g+7
    if (act) *(bf16x8*)(outp + (kkh*64 + lane)*8) = frag;
  }
}

// GEMM2+proj: out = (h1 @ W2) * scale + shift + x @ Wp  (swapped-operand, same acc)
__global__ __launch_bounds__(256) void k_mlp2(const bf16x8* __restrict__ h1s,
        const unsigned short* __restrict__ xb,
        const bf16x8* __restrict__ W2s, const bf16x8* __restrict__ Wps,
        const float* __restrict__ scale, const float* __restrict__ shift,
        float* __restrict__ out)
{
  __shared__ bf16x8 w[2048];   // 32KB weight chunk
  int tid = threadIdx.x, wv = tid >> 6, lane = tid & 63, g = lane >> 4, r = lane & 15;
  int tile0 = blockIdx.x*4 + wv;
  int tile  = min(tile0, NT_ - 1);
  const bf16x8* h1f  = h1s + (size_t)tile*512;
  const bf16x8* xrow = (const bf16x8*)(xb + ((size_t)tile*16 + r)*IND_);

  f32x4 acc[16];
  #pragma unroll
  for (int t = 0; t < 16; t++) acc[t] = (f32x4){0.f,0.f,0.f,0.f};

  for (int q = 0; q < 4; q++){                       // K=256 of W2 in 4 chunks
    __syncthreads();
    #pragma unroll
    for (int i = 0; i < 8; i++) w[tid + i*256] = W2s[q*2048 + tid + i*256];
    __syncthreads();
    #pragma unroll
    for (int km = 0; km < 2; km++){
      bf16x8 Bf = h1f[(2*q + km)*64 + lane];
      #pragma unroll
      for (int t = 0; t < 16; t++)
        acc[t] = __builtin_amdgcn_mfma_f32_16x16x32_bf16(w[(t*2+km)*64 + lane], Bf, acc[t], 0,0,0);
    }
  }
  for (int q = 0; q < 2; q++){                       // K=128 of Wp in 2 chunks
    __syncthreads();
    #pragma unroll
    for (int i = 0; i < 8; i++) w[tid + i*256] = Wps[q*2048 + tid + i*256];
    __syncthreads();
    #pragma unroll
    for (int km = 0; km < 2; km++){
      bf16x8 Bf = xrow[(2*q + km)*4 + g];
      #pragma unroll
      for (int t = 0; t < 16; t++)
        acc[t] = __builtin_amdgcn_mfma_f32_16x16x32_bf16(w[(t*2+km)*64 + lane], Bf, acc[t], 0,0,0);
    }
  }

  if (tile0 < NT_){
    const float4* sc = (const float4*)scale;
    const float4* sh = (const float4*)shift;
    #pragma unroll
    for (int t = 0; t < 16; t++){
      float4 s = sc[t*4 + g], b = sh[t*4 + g];
      f32x4 a = acc[t];
      float4 o;
      o.x = fmaf(a.x, s.x, b.x);
      o.y = fmaf(a.y, s.y, b.y);
      o.z = fmaf(a.z, s.z, b.z);
      o.w = fmaf(a.w, s.w, b.w);
      *(float4*)(out + ((size_t)tile*16 + r)*OUTD_ + t*16 + g*4) = o;
    }
  }
}

extern "C" void kernel_launch(void* const* d_in, const int* in_sizes, int n_in,
                              void* d_out, int out_size, void* d_ws, size_t ws_size,
                              hipStream_t stream)
{
  const float* x     = (const float*)d_in[0];
  const int*   ei    = (const int*)d_in[1];     // [2][E]: src then dst
  const float* eps   = (const float*)d_in[2];
  const float* W1    = (const float*)d_in[3];
  const float* b1    = (const float*)d_in[4];
  const float* W2    = (const float*)d_in[5];
  const float* b2    = (const float*)d_in[6];
  const float* gamma = (const float*)d_in[7];
  const float* beta  = (const float*)d_in[8];
  const float* rmean = (const float*)d_in[9];
  const float* rvar  = (const float*)d_in[10];
  const float* Wp    = (const float*)d_in[11];
  const float* bp    = (const float*)d_in[12];
  float* out = (float*)d_out;

  char* ws = (char*)d_ws; size_t off = 0;
  auto carve = [&](size_t b)->char* { char* p = ws + off; off = (off + b + 255) & ~(size_t)255; return p; };
  unsigned*       h0    = (unsigned*)carve((size_t)N_*IND_*2);
  unsigned*       xbuf  = (unsigned*)carve((size_t)N_*IND_*2);
  unsigned short* h1s   = (unsigned short*)carve((size_t)N_*OUTD_*2);
  unsigned short* W1s   = (unsigned short*)carve(4096*16);
  unsigned short* W2s   = (unsigned short*)carve(8192*16);
  unsigned short* Wps   = (unsigned short*)carve(4096*16);
  float*          scale = (float*)carve(256*4);
  float*          shift = (float*)carve(256*4);
  int*            deg   = (int*)carve((size_t)N_*4);
  int*            cur   = (int*)carve((size_t)N_*4);
  int*            offs  = (int*)carve((size_t)(N_+1)*4);
  int*            adj   = (int*)carve((size_t)E_*4);
  int*            bsum  = (int*)carve((size_t)NB_*4);

  hipMemsetAsync(deg, 0, (size_t)N_*4, stream);
  hipMemsetAsync(cur, 0, (size_t)N_*4, stream);

  k_prep <<<65, 256, 0, stream>>>(W1, W2, Wp, b2, gamma, beta, rmean, rvar, bp,
                                  W1s, W2s, Wps, scale, shift);
  k_deg  <<<(E_+255)/256, 256, 0, stream>>>(ei + E_, deg);
  k_scan1<<<NB_, 1024, 0, stream>>>(deg, bsum, offs);
  k_scan2<<<NB_, 1024, 0, stream>>>(deg, bsum, offs);
  k_fill <<<(E_+255)/256, 256, 0, stream>>>(ei, ei + E_, offs, cur, adj);
  k_agg  <<<(N_+3)/4, 256, 0, stream>>>(x, offs, adj, eps, h0, xbuf);
  k_mlp1 <<<(NT_+3)/4, 256, 0, stream>>>((const unsigned short*)h0, (const bf16x8*)W1s, b1, h1s);
  k_mlp2 <<<(NT_+3)/4, 256, 0, stream>>>((const bf16x8*)h1s, (const unsigned short*)xbuf,
                                         (const bf16x8*)W2s, (const bf16x8*)Wps, scale, shift, out);
}

// Round 3
// 214.097 us; speedup vs baseline: 1.7741x; 1.0826x over previous
//
#include <hip/hip_runtime.h>

#define N_ 100000
#define E_ 600000
#define IND_ 128
#define OUTD_ 256
#define NT_ (N_/16)        // 6250 row-tiles of 16
#define NB_ 98             // scan blocks of 1024: ceil(100000/1024)

typedef __attribute__((ext_vector_type(8))) short bf16x8;
typedef __attribute__((ext_vector_type(4))) float f32x4;
typedef __attribute__((ext_vector_type(2))) unsigned int u32x2;

static __device__ __forceinline__ unsigned f2bf_u(float f){
  union { float f; unsigned u; } v; v.f = f;
  return (v.u + 0x7fffu + ((v.u >> 16) & 1u)) >> 16;   // RNE bf16
}
static __device__ __forceinline__ unsigned pack2(float a, float b){
  return f2bf_u(a) | (f2bf_u(b) << 16);
}

// ---- weight prep: fp32 row-major W[K][256] -> bf16 fragment-order, chunked for 32KB LDS stages
__global__ void k_prep(const float* __restrict__ W1, const float* __restrict__ W2,
                       const float* __restrict__ Wp, const float* __restrict__ b2,
                       const float* __restrict__ gamma, const float* __restrict__ beta,
                       const float* __restrict__ mean, const float* __restrict__ var,
                       const float* __restrict__ bp,
                       unsigned short* __restrict__ W1s, unsigned short* __restrict__ W2s,
                       unsigned short* __restrict__ Wps,
                       float* __restrict__ scale, float* __restrict__ shift)
{
  int gid = blockIdx.x*256 + threadIdx.x;
  if (gid < 16384) {
    const float* W; unsigned short* Ws; int u;
    if (gid < 4096)       { W = W1; Ws = W1s; u = gid; }
    else if (gid < 12288) { W = W2; Ws = W2s; u = gid - 4096; }
    else                  { W = Wp; Ws = Wps; u = gid - 12288; }
    int l  = u & 63;
    int km = (u >> 6) & 1;
    int t  = (u >> 7) & 15;
    int q  = u >> 11;
    int kk = 2*q + km;
    int kb = kk*32 + (l >> 4)*8;
    int c  = 16*t + (l & 15);
    #pragma unroll
    for (int j = 0; j < 8; j++)
      Ws[u*8 + j] = (unsigned short)f2bf_u(W[(size_t)(kb + j)*OUTD_ + c]);
  } else if (gid < 16640) {
    int c = gid - 16384;
    float s = gamma[c] * rsqrtf(var[c] + 1e-5f);
    scale[c] = s;
    shift[c] = (b2[c] - mean[c]) * s + beta[c] + bp[c];
  }
}

__global__ void k_deg(const int* __restrict__ dst, int* __restrict__ deg){
  int e = blockIdx.x*256 + threadIdx.x;
  if (e < E_) atomicAdd(&deg[dst[e]], 1);
}

// hierarchical scan pass 1: per-1024-chunk sums (coalesced, full-machine parallel)
__global__ __launch_bounds__(1024) void k_scan1(const int* __restrict__ deg,
                                                int* __restrict__ bsum, int* __restrict__ offs){
  __shared__ int red[16];
  int tid = threadIdx.x;
  int i = blockIdx.x*1024 + tid;
  int v = (i < N_) ? deg[i] : 0;
  #pragma unroll
  for (int d = 32; d; d >>= 1) v += __shfl_down(v, d);
  if ((tid & 63) == 0) red[tid >> 6] = v;
  __syncthreads();
  if (tid < 16) {
    int s = red[tid];
    #pragma unroll
    for (int d = 8; d; d >>= 1) s += __shfl_down(s, d, 16);
    if (tid == 0) bsum[blockIdx.x] = s;
  }
  if (blockIdx.x == 0 && tid == 0) offs[N_] = E_;
}

// pass 2: each block scans the 98 block sums (redundantly) + its own chunk, writes exclusive offsets
__global__ __launch_bounds__(1024) void k_scan2(const int* __restrict__ deg,
                                                const int* __restrict__ bsum, int* __restrict__ offs){
  __shared__ int bs[128];
  __shared__ int d1[1024];
  int tid = threadIdx.x;
  if (tid < 128) bs[tid] = (tid < NB_) ? bsum[tid] : 0;
  __syncthreads();
  #pragma unroll
  for (int d = 1; d < 128; d <<= 1){
    int v = (tid < 128 && tid >= d) ? bs[tid - d] : 0;
    __syncthreads();
    if (tid < 128) bs[tid] += v;
    __syncthreads();
  }
  int bprefix = (blockIdx.x > 0) ? bs[blockIdx.x - 1] : 0;
  int i = blockIdx.x*1024 + tid;
  int v = (i < N_) ? deg[i] : 0;
  d1[tid] = v;
  __syncthreads();
  #pragma unroll
  for (int d = 1; d < 1024; d <<= 1){
    int t = (tid >= d) ? d1[tid - d] : 0;
    __syncthreads();
    d1[tid] += t;
    __syncthreads();
  }
  if (i < N_) offs[i] = bprefix + d1[tid] - v;
}

__global__ void k_fill(const int* __restrict__ src, const int* __restrict__ dst,
                       const int* __restrict__ offs, int* __restrict__ cur, int* __restrict__ adj){
  int e = blockIdx.x*256 + threadIdx.x;
  if (e < E_) {
    int d = dst[e];
    int p = atomicAdd(&cur[d], 1);
    adj[offs[d] + p] = src[e];
  }
}

// one wave per dst row; lane holds cols {2L, 2L+1}.
// Neighbor indices: one coalesced 64-lane load + __shfl broadcast (no dependent-load chain);
// gather unrolled x4 with independent accumulators for memory-level parallelism.
__global__ void k_agg(const float* __restrict__ x, const int* __restrict__ offs,
                      const int* __restrict__ adj, const float* __restrict__ epsp,
                      unsigned* __restrict__ h0, unsigned* __restrict__ xb)
{
  int row  = blockIdx.x*4 + (threadIdx.x >> 6);
  int lane = threadIdx.x & 63;
  if (row >= N_) return;
  const float2* xr = (const float2*)(x + (size_t)row*IND_);
  float2 xv = xr[lane];
  float ax0=0.f, ay0=0.f, ax1=0.f, ay1=0.f, ax2=0.f, ay2=0.f, ax3=0.f, ay3=0.f;
  int b = offs[row], e = offs[row+1];
  for (int base = b; base < e; base += 64){
    int cnt = min(64, e - base);
    int idx = adj[base + min(lane, cnt - 1)];   // coalesced; all indices for this pass
    int j = 0;
    for (; j + 4 <= cnt; j += 4){
      int n0 = __shfl(idx, j+0);
      int n1 = __shfl(idx, j+1);
      int n2 = __shfl(idx, j+2);
      int n3 = __shfl(idx, j+3);
      float2 v0 = ((const float2*)(x + (size_t)n0*IND_))[lane];
      float2 v1 = ((const float2*)(x + (size_t)n1*IND_))[lane];
      float2 v2 = ((const float2*)(x + (size_t)n2*IND_))[lane];
      float2 v3 = ((const float2*)(x + (size_t)n3*IND_))[lane];
      ax0 += v0.x; ay0 += v0.y;
      ax1 += v1.x; ay1 += v1.y;
      ax2 += v2.x; ay2 += v2.y;
      ax3 += v3.x; ay3 += v3.y;
    }
    for (; j < cnt; j++){
      int n = __shfl(idx, j);
      float2 v = ((const float2*)(x + (size_t)n*IND_))[lane];
      ax0 += v.x; ay0 += v.y;
    }
  }
  float ax = (ax0 + ax1) + (ax2 + ax3);
  float ay = (ay0 + ay1) + (ay2 + ay3);
  float k1 = 1.f + epsp[0];
  h0[(size_t)row*64 + lane] = pack2(fmaf(k1, xv.x, ax), fmaf(k1, xv.y, ay));
  xb[(size_t)row*64 + lane] = pack2(xv.x, xv.y);
}

// GEMM1: h1 = relu(h0 @ W1 + b1), swapped-operand MFMA; h1 written in B-fragment order
__global__ __launch_bounds__(256) void k_mlp1(const unsigned short* __restrict__ h0,
        const bf16x8* __restrict__ W1s, const float* __restrict__ b1,
        unsigned short* __restrict__ h1s)
{
  __shared__ bf16x8 w[2048];                       // 32KB weight chunk
  __shared__ __align__(16) char trans[4][2][1280]; // per-wave 16x(64B+16B pad), double-buffered
  int tid = threadIdx.x;
  int wv = tid >> 6, lane = tid & 63, g = lane >> 4, r = lane & 15;
  int tile0 = blockIdx.x*4 + wv;
  int tile  = min(tile0, NT_ - 1);

  const bf16x8* hrow = (const bf16x8*)(h0 + ((size_t)tile*16 + r)*IND_);
  bf16x8 B[4];
  #pragma unroll
  for (int kk = 0; kk < 4; kk++) B[kk] = hrow[kk*4 + g];

  f32x4 acc[16];
  #pragma unroll
  for (int t = 0; t < 16; t++) acc[t] = (f32x4){0.f,0.f,0.f,0.f};

  for (int q = 0; q < 2; q++){
    __syncthreads();
    #pragma unroll
    for (int i = 0; i < 8; i++) w[tid + i*256] = W1s[q*2048 + tid + i*256];
    __syncthreads();
    #pragma unroll
    for (int km = 0; km < 2; km++){
      bf16x8 Bf = B[2*q + km];
      #pragma unroll
      for (int t = 0; t < 16; t++)
        acc[t] = __builtin_amdgcn_mfma_f32_16x16x32_bf16(w[(t*2+km)*64 + lane], Bf, acc[t], 0,0,0);
    }
  }

  // epilogue: bias+relu -> bf16, per-32-col LDS regroup (4g+q -> 8g+j), coalesced frag-order store
  const float4* b1v = (const float4*)b1;
  unsigned short* outp = h1s + (size_t)tile*4096;
  bool act = (tile0 < NT_);
  #pragma unroll
  for (int kkh = 0; kkh < 8; kkh++){
    char* tr = &trans[wv][kkh & 1][0];
    #pragma unroll
    for (int h = 0; h < 2; h++){
      int t = 2*kkh + h;
      float4 bb = b1v[t*4 + g];
      f32x4 a = acc[t];
      float v0 = fmaxf(a.x + bb.x, 0.f);
      float v1 = fmaxf(a.y + bb.y, 0.f);
      float v2 = fmaxf(a.z + bb.z, 0.f);
      float v3 = fmaxf(a.w + bb.w, 0.f);
      u32x2 dd; dd.x = pack2(v0, v1); dd.y = pack2(v2, v3);
      *(u32x2*)(tr + r*80 + h*32 + g*8) = dd;   // row r, cols 16h+4g..+3
    }
    bf16x8 frag = *(const bf16x8*)(tr + r*80 + g*16);   // row r, cols 8g..8g+7
    if (act) *(bf16x8*)(outp + (kkh*64 + lane)*8) = frag;
  }
}

// GEMM2+proj: out = (h1 @ W2) * scale + shift + x @ Wp  (swapped-operand, same acc)
__global__ __launch_bounds__(256) void k_mlp2(const bf16x8* __restrict__ h1s,
        const unsigned short* __restrict__ xb,
        const bf16x8* __restrict__ W2s, const bf16x8* __restrict__ Wps,
        const float* __restrict__ scale, const float* __restrict__ shift,
        float* __restrict__ out)
{
  __shared__ bf16x8 w[2048];   // 32KB weight chunk
  int tid = threadIdx.x, wv = tid >> 6, lane = tid & 63, g = lane >> 4, r = lane & 15;
  int tile0 = blockIdx.x*4 + wv;
  int tile  = min(tile0, NT_ - 1);
  const bf16x8* h1f  = h1s + (size_t)tile*512;
  const bf16x8* xrow = (const bf16x8*)(xb + ((size_t)tile*16 + r)*IND_);

  f32x4 acc[16];
  #pragma unroll
  for (int t = 0; t < 16; t++) acc[t] = (f32x4){0.f,0.f,0.f,0.f};

  for (int q = 0; q < 4; q++){                       // K=256 of W2 in 4 chunks
    __syncthreads();
    #pragma unroll
    for (int i = 0; i < 8; i++) w[tid + i*256] = W2s[q*2048 + tid + i*256];
    __syncthreads();
    #pragma unroll
    for (int km = 0; km < 2; km++){
      bf16x8 Bf = h1f[(2*q + km)*64 + lane];
      #pragma unroll
      for (int t = 0; t < 16; t++)
        acc[t] = __builtin_amdgcn_mfma_f32_16x16x32_bf16(w[(t*2+km)*64 + lane], Bf, acc[t], 0,0,0);
    }
  }
  for (int q = 0; q < 2; q++){                       // K=128 of Wp in 2 chunks
    __syncthreads();
    #pragma unroll
    for (int i = 0; i < 8; i++) w[tid + i*256] = Wps[q*2048 + tid + i*256];
    __syncthreads();
    #pragma unroll
    for (int km = 0; km < 2; km++){
      bf16x8 Bf = xrow[(2*q + km)*4 + g];
      #pragma unroll
      for (int t = 0; t < 16; t++)
        acc[t] = __builtin_amdgcn_mfma_f32_16x16x32_bf16(w[(t*2+km)*64 + lane], Bf, acc[t], 0,0,0);
    }
  }

  if (tile0 < NT_){
    const float4* sc = (const float4*)scale;
    const float4* sh = (const float4*)shift;
    #pragma unroll
    for (int t = 0; t < 16; t++){
      float4 s = sc[t*4 + g], b = sh[t*4 + g];
      f32x4 a = acc[t];
      float4 o;
      o.x = fmaf(a.x, s.x, b.x);
      o.y = fmaf(a.y, s.y, b.y);
      o.z = fmaf(a.z, s.z, b.z);
      o.w = fmaf(a.w, s.w, b.w);
      *(float4*)(out + ((size_t)tile*16 + r)*OUTD_ + t*16 + g*4) = o;
    }
  }
}

extern "C" void kernel_launch(void* const* d_in, const int* in_sizes, int n_in,
                              void* d_out, int out_size, void* d_ws, size_t ws_size,
                              hipStream_t stream)
{
  const float* x     = (const float*)d_in[0];
  const int*   ei    = (const int*)d_in[1];     // [2][E]: src then dst
  const float* eps   = (const float*)d_in[2];
  const float* W1    = (const float*)d_in[3];
  const float* b1    = (const float*)d_in[4];
  const float* W2    = (const float*)d_in[5];
  const float* b2    = (const float*)d_in[6];
  const float* gamma = (const float*)d_in[7];
  const float* beta  = (const float*)d_in[8];
  const float* rmean = (const float*)d_in[9];
  const float* rvar  = (const float*)d_in[10];
  const float* Wp    = (const float*)d_in[11];
  const float* bp    = (const float*)d_in[12];
  float* out = (float*)d_out;

  char* ws = (char*)d_ws; size_t off = 0;
  auto carve = [&](size_t b)->char* { char* p = ws + off; off = (off + b + 255) & ~(size_t)255; return p; };
  unsigned*       h0    = (unsigned*)carve((size_t)N_*IND_*2);
  unsigned*       xbuf  = (unsigned*)carve((size_t)N_*IND_*2);
  unsigned short* h1s   = (unsigned short*)carve((size_t)N_*OUTD_*2);
  unsigned short* W1s   = (unsigned short*)carve(4096*16);
  unsigned short* W2s   = (unsigned short*)carve(8192*16);
  unsigned short* Wps   = (unsigned short*)carve(4096*16);
  float*          scale = (float*)carve(256*4);
  float*          shift = (float*)carve(256*4);
  int*            deg   = (int*)carve((size_t)N_*4);
  int*            cur   = (int*)carve((size_t)N_*4);
  int*            offs  = (int*)carve((size_t)(N_+1)*4);
  int*            adj   = (int*)carve((size_t)E_*4);
  int*            bsum  = (int*)carve((size_t)NB_*4);

  hipMemsetAsync(deg, 0, (size_t)N_*4, stream);
  hipMemsetAsync(cur, 0, (size_t)N_*4, stream);

  k_prep <<<65, 256, 0, stream>>>(W1, W2, Wp, b2, gamma, beta, rmean, rvar, bp,
                                  W1s, W2s, Wps, scale, shift);
  k_deg  <<<(E_+255)/256, 256, 0, stream>>>(ei + E_, deg);
  k_scan1<<<NB_, 1024, 0, stream>>>(deg, bsum, offs);
  k_scan2<<<NB_, 1024, 0, stream>>>(deg, bsum, offs);
  k_fill <<<(E_+255)/256, 256, 0, stream>>>(ei, ei + E_, offs, cur, adj);
  k_agg  <<<(N_+3)/4, 256, 0, stream>>>(x, offs, adj, eps, h0, xbuf);
  k_mlp1 <<<(NT_+3)/4, 256, 0, stream>>>((const unsigned short*)h0, (const bf16x8*)W1s, b1, h1s);
  k_mlp2 <<<(NT_+3)/4, 256, 0, stream>>>((const bf16x8*)h1s, (const unsigned short*)xbuf,
                                         (const bf16x8*)W2s, (const bf16x8*)Wps, scale, shift, out);
}